// Round 8
// baseline (225.116 us; speedup 1.0000x reference)
//
#include <hip/hip_runtime.h>
#include <hip/hip_bf16.h>
#include <stdint.h>

typedef __attribute__((ext_vector_type(8))) short bf8;
typedef __attribute__((ext_vector_type(4))) float f4;

#define MFMA16(a, b, c) __builtin_amdgcn_mfma_f32_16x16x32_bf16((a), (b), (c), 0, 0, 0)

static __device__ __forceinline__ short f2b(float f) {
  uint32_t x = __float_as_uint(f);
  x += 0x7fffu + ((x >> 16) & 1u);
  return (short)(x >> 16);
}

static __device__ __forceinline__ float b2f(short v) {
  return __uint_as_float(((uint32_t)(uint16_t)v) << 16);
}

// pack two nonnegative f32 into 2x bf16 (round-half-up, <0.5 ulp bias)
static __device__ __forceinline__ uint32_t pk2(float a, float b) {
  return ((__float_as_uint(a) + 0x8000u) >> 16) |
         ((__float_as_uint(b) + 0x8000u) & 0xffff0000u);
}

// async global->LDS, 16B per lane; LDS dest = wave-uniform base + lane*16
static __device__ __forceinline__ void gload16(const short* g, void* l) {
  __builtin_amdgcn_global_load_lds(
      (const __attribute__((address_space(1))) void*)g,
      (__attribute__((address_space(3))) void*)l, 16, 0, 0);
}

// rope table: tab[s*32 + i] = (cos(s*invf_i), sin(s*invf_i)), s<2048, i<32
__global__ void rope_kernel(float2* __restrict__ tab) {
  const int t = blockIdx.x * 256 + threadIdx.x;
  const int s = t >> 5, i = t & 31;
  const float inv = powf(10000.0f, -(float)i * (1.0f / 32.0f));
  const float ang = (float)s * inv;
  float sv, cv;
  sincosf(ang, &sv, &cv);
  tab[t] = make_float2(cv, sv);
}

// one-shot f32->bf16: x (4194304) -> xb; wq,wk,wv,wo (1048576 each) -> Wb[4][1<<20]
__global__ void convert_kernel(const float* __restrict__ x,
                               const float* __restrict__ wq, const float* __restrict__ wk,
                               const float* __restrict__ wv, const float* __restrict__ wo,
                               short* __restrict__ xb, short* __restrict__ Wb) {
  const size_t i = ((size_t)blockIdx.x * 256 + threadIdx.x) * 8;
  const float* __restrict__ src;
  short* __restrict__ dst;
  if (i < 4194304u) {
    src = x + i;
    dst = xb + i;
  } else {
    const size_t j = i - 4194304u;
    const int z = (int)(j >> 20);
    const size_t o = j & 1048575u;
    src = (z == 0 ? wq : z == 1 ? wk : z == 2 ? wv : wo) + o;
    dst = Wb + j;
  }
  const float4 a = *(const float4*)src;
  const float4 b = *(const float4*)(src + 4);
  bf8 v;
  v[0] = f2b(a.x); v[1] = f2b(a.y); v[2] = f2b(a.z); v[3] = f2b(a.w);
  v[4] = f2b(b.x); v[5] = f2b(b.y); v[6] = f2b(b.z); v[7] = f2b(b.w);
  *(bf8*)dst = v;
}

// C = A @ W^T, pure-bf16. 128x128 tiles, BK=64, 4 waves each 64x64.
// Staging via global_load_lds (16B) with inverse-swizzled global source
// (rule-21: linear dest + inv-swz source + swz read).
// MODE 0: W = Wb[blockIdx.z], z<2 -> RoPE Q/K epilogue; z==2 -> V^T epilogue
// MODE 1: W = Wb[3] (Wo), f32 epilogue -> [m][n]
template <int MODE>
__launch_bounds__(256, 2)
__global__ void gemm_kernel(const short* __restrict__ Ab, const short* __restrict__ Wb,
                            short* __restrict__ Qo, short* __restrict__ Ko,
                            short* __restrict__ VTo, float* __restrict__ Fo,
                            const float2* __restrict__ rope) {
  constexpr int K = 1024;
  const int bm = blockIdx.x, bn = blockIdx.y;
  const int z = (MODE == 0) ? blockIdx.z : 3;
  const short* __restrict__ Bb = Wb + ((size_t)z << 20);

  __shared__ short As[128 * 64];
  __shared__ short Bs[128 * 64];

  const int tid = threadIdx.x;
  const int lane = tid & 63;
  const int wave = tid >> 6;
  const int wr = wave >> 1, wc = wave & 1;
  const int lg = lane >> 4, lr = lane & 15;

  f4 acc[4][4];
#pragma unroll
  for (int i = 0; i < 4; i++)
#pragma unroll
    for (int j = 0; j < 4; j++) {
      acc[i][j][0] = 0.f; acc[i][j][1] = 0.f;
      acc[i][j][2] = 0.f; acc[i][j][3] = 0.f;
    }

  const int kc = tid & 7;     // 16B k-chunk within 64-wide slice
  const int srow = tid >> 3;  // 0..31
  const int kcs = (kc ^ (srow & 7)) * 8;  // inverse-swizzled source chunk
  char* const Asw = (char*)As + wave * 1024;
  char* const Bsw = (char*)Bs + wave * 1024;

  for (int k0 = 0; k0 < K; k0 += 64) {
#pragma unroll
    for (int i = 0; i < 4; i++) {
      const int row = srow + i * 32;
      gload16(Ab + (size_t)(bm * 128 + row) * K + k0 + kcs, Asw + i * 4096);
      gload16(Bb + (size_t)(bn * 128 + row) * K + k0 + kcs, Bsw + i * 4096);
    }
    __syncthreads();
#pragma unroll
    for (int kk = 0; kk < 2; kk++) {
      bf8 af[4], bb[4];
#pragma unroll
      for (int mi = 0; mi < 4; mi++) {
        const int row = wr * 64 + mi * 16 + lr;
        const int lb = (row * 128 + kk * 64 + lg * 16) ^ ((row & 7) << 4);
        af[mi] = *(const bf8*)((const char*)As + lb);
      }
#pragma unroll
      for (int ni = 0; ni < 4; ni++) {
        const int row = wc * 64 + ni * 16 + lr;
        const int lb = (row * 128 + kk * 64 + lg * 16) ^ ((row & 7) << 4);
        bb[ni] = *(const bf8*)((const char*)Bs + lb);
      }
#pragma unroll
      for (int mi = 0; mi < 4; mi++)
#pragma unroll
        for (int ni = 0; ni < 4; ni++)
          acc[mi][ni] = MFMA16(af[mi], bb[ni], acc[mi][ni]);
    }
    __syncthreads();
  }

  if (MODE == 1) {
#pragma unroll
    for (int mi = 0; mi < 4; mi++) {
      const int m0 = bm * 128 + wr * 64 + mi * 16 + lg * 4;
#pragma unroll
      for (int ni = 0; ni < 4; ni++) {
        const int n = bn * 128 + wc * 64 + ni * 16 + lr;
#pragma unroll
        for (int r = 0; r < 4; r++)
          Fo[(size_t)(m0 + r) * 1024 + n] = acc[mi][ni][r];
      }
    }
    return;
  }

  if (z == 2) {  // V^T: [b][h][64][s]
#pragma unroll
    for (int mi = 0; mi < 4; mi++) {
      const int m0 = bm * 128 + wr * 64 + mi * 16 + lg * 4;
      const int b = m0 >> 11, s0 = m0 & 2047;
#pragma unroll
      for (int ni = 0; ni < 4; ni++) {
        const int n = bn * 128 + wc * 64 + ni * 16 + lr;
        ushort4 pk;
        pk.x = (unsigned short)f2b(acc[mi][ni][0]);
        pk.y = (unsigned short)f2b(acc[mi][ni][1]);
        pk.z = (unsigned short)f2b(acc[mi][ni][2]);
        pk.w = (unsigned short)f2b(acc[mi][ni][3]);
        *(ushort4*)(VTo + ((size_t)((b * 16 + (n >> 6)) * 64 + (n & 63))) * 2048 + s0) = pk;
      }
    }
  } else {  // Q or K with RoPE: [b][h][s][64]
    short* __restrict__ Out = (z == 0) ? Qo : Ko;
    // Q gets the attention scale folded with log2(e) so softmax can use exp2
    const float qscale = (z == 0) ? 0.18033688011112042f : 1.0f;  // 0.125*log2(e)
#pragma unroll
    for (int mi = 0; mi < 4; mi++) {
      const int m0 = bm * 128 + wr * 64 + mi * 16 + lg * 4;
      const int b = m0 >> 11, s0 = m0 & 2047;
#pragma unroll
      for (int ni = 0; ni < 4; ni++) {
        const int n = bn * 128 + wc * 64 + ni * 16 + lr;
        const int h = n >> 6, d = n & 63;
        const float sgn = (d & 1) ? 1.0f : -1.0f;
#pragma unroll
        for (int r = 0; r < 4; r++) {
          const float v = acc[mi][ni][r];
          const float p = __shfl_xor(v, 1);  // partner head-dim (d^1)
          const float2 cs = rope[((s0 + r) << 5) + (d >> 1)];
          const float res = (v * cs.x + sgn * p * cs.y) * qscale;
          Out[((size_t)(b * 16 + h) * 2048 + (s0 + r)) * 64 + d] = f2b(res);
        }
      }
    }
  }
}

// Flash attention, causal, KV-SEGMENT-SPLIT for occupancy.
// Wave w of block (bh, i, seg) owns tile pair tL = 4i+w (rows [tL*16,+16)) and
// tH = 127-tL. With this pairing nkv(L) = i+1 and nkv(H) = 32-i are UNIFORM
// across the block's 4 waves -> zero divergence. seg0 = KV rounds [0,16)
// (L completes here; H partial), seg1 = rounds [16, 32-i) (H only).
// 1024 equal-ish blocks, 40KB LDS -> 4 blocks/CU = 16 waves/CU (perfect fit).
// H partials: normalized o-hat -> AO rows (seg0) / PO1 (seg1) + (m,l); a merge
// kernel combines. P tile single-buffered (reused across the two tiles).
__launch_bounds__(256, 4)
__global__ void attn_kernel(const short* __restrict__ Qg, const short* __restrict__ Kg,
                            const short* __restrict__ Vg, short* __restrict__ AO,
                            short* __restrict__ PO1, float* __restrict__ PM,
                            float* __restrict__ PL) {
  const int S = 2048;
  const int id = blockIdx.x;
  const int xcd = id & 7;
  const int rest = id >> 3;            // 0..127
  const int bh = xcd * 4 + (rest & 3); // XCD-clustered: 4 bh per XCD
  const int rem = rest >> 2;           // 0..31
  const int seg = rem & 1;
  const int i = rem >> 1;              // 0..15
  const int tid = threadIdx.x;
  const int lane = tid & 63, wave = tid >> 6;
  const int lg = lane >> 4, lr = lane & 15;
  const short* __restrict__ Qp = Qg + (size_t)bh * S * 64;
  const short* __restrict__ Kp = Kg + (size_t)bh * S * 64;
  const short* __restrict__ Vp = Vg + (size_t)bh * 64 * S;

  __shared__ short KB[2][64 * 64];  // K tile, swizzled (8KB each)
  __shared__ short VB[2][64 * 64];  // V^T tile, swizzled
  __shared__ short PB[4][16 * 64];  // per-wave P tile (2KB), reused by both tts

  const int tL = 4 * i + wave;         // 0..63
  const int tH = 127 - tL;             // 64..127
  const int qbaseT[2] = {tH << 4, tL << 4};
  const int nkvL = i + 1;              // uniform across waves
  const int nkvH = 32 - i;             // uniform across waves
  const int k0 = seg ? 16 : 0;
  const int kend = seg ? nkvH : 16;    // rounds [k0, kend)

  // staging: per wave 2 calls per tile; call c covers rows (2w+c)*8 + (lane>>3)
  const int rsub = lane >> 3;                 // 0..7
  const int chsw = ((lane & 7) ^ rsub) * 8;   // inv-swizzled chunk (shorts)
  const int row0 = (2 * wave) * 8 + rsub;
  const int row1 = (2 * wave + 1) * 8 + rsub;

#define STAGE_KV(buf, kvb_)                                                        \
  do {                                                                             \
    gload16(Kp + (size_t)((kvb_) + row0) * 64 + chsw, (char*)KB[buf] + (2 * wave) * 1024);     \
    gload16(Kp + (size_t)((kvb_) + row1) * 64 + chsw, (char*)KB[buf] + (2 * wave + 1) * 1024); \
    gload16(Vp + (size_t)row0 * 2048 + (kvb_) + chsw, (char*)VB[buf] + (2 * wave) * 1024);     \
    gload16(Vp + (size_t)row1 * 2048 + (kvb_) + chsw, (char*)VB[buf] + (2 * wave + 1) * 1024); \
  } while (0)

  bf8 qf[2][2];
#pragma unroll
  for (int ks = 0; ks < 2; ks++)
    qf[0][ks] = *(const bf8*)(Qp + (size_t)(qbaseT[0] + lr) * 64 + ks * 32 + lg * 8);
  if (seg == 0) {
#pragma unroll
    for (int ks = 0; ks < 2; ks++)
      qf[1][ks] = *(const bf8*)(Qp + (size_t)(qbaseT[1] + lr) * 64 + ks * 32 + lg * 8);
  }

  f4 o[2][4];
#pragma unroll
  for (int tt = 0; tt < 2; tt++)
#pragma unroll
    for (int dt = 0; dt < 4; dt++) {
      o[tt][dt][0] = 0.f; o[tt][dt][1] = 0.f; o[tt][dt][2] = 0.f; o[tt][dt][3] = 0.f;
    }
  float mrun[2] = {-1e30f, -1e30f};
  float lsum[2] = {0.f, 0.f};

  char* const Pw = (char*)&PB[wave][0];
  const int rowoff = lr * 128;
  const int sw = (lr & 7) << 4;

  STAGE_KV(0, k0 * 64);
  __syncthreads();

  for (int kb = k0; kb < kend; kb++) {
    const int kvb = kb * 64;
    const int cur = (kb - k0) & 1;

    if (kb + 1 < kend) STAGE_KV(cur ^ 1, kvb + 64);

    const char* Kc = (const char*)KB[cur];
    const char* Vc = (const char*)VB[cur];

    // K and V fragments ONCE per round, shared by both tiles
    bf8 kf[4][2], vf[4][2];
#pragma unroll
    for (int nt = 0; nt < 4; nt++) {
      const int row = nt * 16 + lr;
      const int base = row * 128 + lg * 16;
      const int rsw = (row & 7) << 4;
      kf[nt][0] = *(const bf8*)(Kc + (base ^ rsw));
      kf[nt][1] = *(const bf8*)(Kc + ((base + 64) ^ rsw));
      vf[nt][0] = *(const bf8*)(Vc + (base ^ rsw));
      vf[nt][1] = *(const bf8*)(Vc + ((base + 64) ^ rsw));
    }

#pragma unroll
    for (int tt = 0; tt < 2; tt++) {
      // tt=0 (H): always active in [k0,kend); tt=1 (L): seg0 rounds < nkvL.
      // Both predicates are block-uniform -> no divergence.
      if (tt == 1 && (seg != 0 || kb >= nkvL)) continue;

      // swapped QK^T: st[nt] = S^T[kv = kvb+nt*16+lg*4+r][q = qbaseT+lr]
      f4 st[4];
      __builtin_amdgcn_s_setprio(1);
#pragma unroll
      for (int nt = 0; nt < 4; nt++) {
        f4 c;
        c[0] = 0.f; c[1] = 0.f; c[2] = 0.f; c[3] = 0.f;
        c = MFMA16(kf[nt][0], qf[tt][0], c);
        c = MFMA16(kf[nt][1], qf[tt][1], c);
        st[nt] = c;
      }
      __builtin_amdgcn_s_setprio(0);

      if ((kvb + 63) > qbaseT[tt]) {  // causal mask (diagonal round only)
        const int q = qbaseT[tt] + lr;
#pragma unroll
        for (int nt = 0; nt < 4; nt++)
#pragma unroll
          for (int rr = 0; rr < 4; rr++) {
            const int kv = kvb + nt * 16 + lg * 4 + rr;
            if (kv > q) st[nt][rr] = -1e9f;
          }
      }

      // per-q tile max: in-lane tree + 2 cross-lg shfls
      float m0 = fmaxf(fmaxf(st[0][0], st[0][1]), fmaxf(st[0][2], st[0][3]));
#pragma unroll
      for (int nt = 1; nt < 4; nt++)
        m0 = fmaxf(m0, fmaxf(fmaxf(st[nt][0], st[nt][1]), fmaxf(st[nt][2], st[nt][3])));
      m0 = fmaxf(m0, __shfl_xor(m0, 16));
      m0 = fmaxf(m0, __shfl_xor(m0, 32));

      // defer-max: rescale only on threshold growth (exp2 domain)
      if (__any(m0 - mrun[tt] > 8.0f)) {
        const float mn = fmaxf(mrun[tt], m0);
        const float corr = __builtin_amdgcn_exp2f(mrun[tt] - mn);
        mrun[tt] = mn;
        lsum[tt] *= corr;
#pragma unroll
        for (int rr = 0; rr < 4; rr++) {
          const float co = __shfl(corr, (lg << 2) + rr);  // o-layout q
#pragma unroll
          for (int dt = 0; dt < 4; dt++) o[tt][dt][rr] *= co;
        }
      }

      // WAR guard: all prior P reads (prev tt / prev round) drained
      asm volatile("s_waitcnt lgkmcnt(0)" ::: "memory");

      // P = exp2(st - m); in-lane partial sums; 4 kv -> one b64 store
#pragma unroll
      for (int nt = 0; nt < 4; nt++) {
        const float p0 = __builtin_amdgcn_exp2f(st[nt][0] - mrun[tt]);
        const float p1 = __builtin_amdgcn_exp2f(st[nt][1] - mrun[tt]);
        const float p2 = __builtin_amdgcn_exp2f(st[nt][2] - mrun[tt]);
        const float p3 = __builtin_amdgcn_exp2f(st[nt][3] - mrun[tt]);
        lsum[tt] += (p0 + p1) + (p2 + p3);
        *(uint2*)(Pw + ((rowoff + nt * 32 + lg * 8) ^ sw)) =
            make_uint2(pk2(p0, p1), pk2(p2, p3));
      }

      // RAW guard: all lanes' P writes visible before fragment reads
      asm volatile("s_waitcnt lgkmcnt(0)" ::: "memory");

      bf8 pf[2];
#pragma unroll
      for (int ks = 0; ks < 2; ks++)
        pf[ks] = *(const bf8*)(Pw + ((rowoff + ks * 64 + lg * 16) ^ sw));

      __builtin_amdgcn_s_setprio(1);
#pragma unroll
      for (int dt = 0; dt < 4; dt++) {
        o[tt][dt] = MFMA16(pf[0], vf[dt][0], o[tt][dt]);
        o[tt][dt] = MFMA16(pf[1], vf[dt][1], o[tt][dt]);
      }
      __builtin_amdgcn_s_setprio(0);
    }

    // barrier (drains vmcnt: staged buffer complete) once per round
    __syncthreads();
  }

  const int b = bh >> 4, h = bh & 15;
  const int pt = bh * 64 + (tH - 64);

  // H tile (tt=0): normalized partial o-hat + (m,l). seg0 -> AO rows; seg1 -> PO1.
  {
    float s = lsum[0];
    s += __shfl_xor(s, 16);
    s += __shfl_xor(s, 32);
    if (lg == 0) {
      PM[(seg * 2048 + pt) * 16 + lr] = mrun[0];
      PL[(seg * 2048 + pt) * 16 + lr] = s;
    }
    const float inv = 1.0f / s;
    float inv_o[4];
#pragma unroll
    for (int rr = 0; rr < 4; rr++) inv_o[rr] = __shfl(inv, (lg << 2) + rr);
#pragma unroll
    for (int rr = 0; rr < 4; rr++) {
      const int row = lg * 4 + rr;
#pragma unroll
      for (int dt = 0; dt < 4; dt++) {
        const int d = dt * 16 + lr;
        const short v = f2b(o[0][dt][rr] * inv_o[rr]);
        if (seg == 0) {
          const int q = qbaseT[0] + row;
          AO[((size_t)b * 2048 + q) * 1024 + h * 64 + d] = v;
        } else {
          PO1[((size_t)pt * 16 + row) * 64 + d] = v;
        }
      }
    }
  }

  // L tile (tt=1): complete in seg0 -> final normalized AO write
  if (seg == 0) {
    float s = lsum[1];
    s += __shfl_xor(s, 16);
    s += __shfl_xor(s, 32);
    const float inv = 1.0f / s;
    float inv_o[4];
#pragma unroll
    for (int rr = 0; rr < 4; rr++) inv_o[rr] = __shfl(inv, (lg << 2) + rr);
#pragma unroll
    for (int rr = 0; rr < 4; rr++) {
      const int q = qbaseT[1] + lg * 4 + rr;
#pragma unroll
      for (int dt = 0; dt < 4; dt++) {
        const int d = dt * 16 + lr;
        AO[((size_t)b * 2048 + q) * 1024 + h * 64 + d] = f2b(o[1][dt][rr] * inv_o[rr]);
      }
    }
  }
#undef STAGE_KV
}

// merge the two softmax segments for H tiles (q rows [1024, 2048) per bh)
__global__ void merge_kernel(short* __restrict__ AO, const short* __restrict__ PO1,
                             const float* __restrict__ PM, const float* __restrict__ PL) {
  const int pt = blockIdx.x;          // 0..2047
  const int bh = pt >> 6, tH = 64 + (pt & 63);
  const int b = bh >> 4, h = bh & 15;
  const int d = threadIdx.x;          // 0..63
#pragma unroll 4
  for (int r = 0; r < 16; r++) {
    const float m0 = PM[pt * 16 + r];
    const float m1 = PM[(2048 + pt) * 16 + r];
    const float l0 = PL[pt * 16 + r];
    const float l1 = PL[(2048 + pt) * 16 + r];
    const float m = fmaxf(m0, m1);
    const float w0 = l0 * __builtin_amdgcn_exp2f(m0 - m);
    const float w1 = l1 * __builtin_amdgcn_exp2f(m1 - m);
    const float wi = 1.0f / (w0 + w1);
    const int q = tH * 16 + r;
    const size_t ao = ((size_t)b * 2048 + q) * 1024 + h * 64 + d;
    const float o0 = b2f(AO[ao]);
    const float o1 = b2f(PO1[((size_t)pt * 16 + r) * 64 + d]);
    AO[ao] = f2b((o0 * w0 + o1 * w1) * wi);
  }
}

extern "C" void kernel_launch(void* const* d_in, const int* in_sizes, int n_in,
                              void* d_out, int out_size, void* d_ws, size_t ws_size,
                              hipStream_t stream) {
  const float* x  = (const float*)d_in[0];
  const float* wq = (const float*)d_in[1];
  const float* wk = (const float*)d_in[2];
  const float* wv = (const float*)d_in[3];
  const float* wo = (const float*)d_in[4];
  float* out = (float*)d_out;

  char* ws = (char*)d_ws;
  short*  Qb  = (short*)(ws);                       // 8 MB  [b][h][s][64] bf16 (pre-scaled)
  short*  Kb  = (short*)(ws + (8ull  << 20));       // 8 MB
  short*  VTb = (short*)(ws + (16ull << 20));       // 8 MB  [b][h][64][s] bf16
  short*  AOb = (short*)(ws + (24ull << 20));       // 8 MB  [b][s][1024] bf16 (aliases xb)
  short*  xb  = AOb;                                // xb dead before attn writes AOb
  short*  Wb  = (short*)(ws + (32ull << 20));       // 8 MB  [4][1024][1024] bf16
  float2* tab = (float2*)(ws + (40ull << 20));      // 512 KB rope table
  // attn partials overlay dead regions (Wq/Wk/Wv dead after gemm<0>):
  short*  PO1 = (short*)(ws + (32ull << 20));            // 4 MB  [2048][16][64] bf16
  float*  PM  = (float*)(ws + (36ull << 20));            // 256 KB [2][2048][16]
  float*  PL  = (float*)(ws + (36ull << 20) + (1u << 18)); // 256 KB

  convert_kernel<<<4096, 256, 0, stream>>>(x, wq, wk, wv, wo, xb, Wb);
  rope_kernel<<<256, 256, 0, stream>>>(tab);
  gemm_kernel<0><<<dim3(32, 8, 3), 256, 0, stream>>>(
      xb, Wb, Qb, Kb, VTb, nullptr, tab);
  attn_kernel<<<1024, 256, 0, stream>>>(Qb, Kb, VTb, AOb, PO1, PM, PL);
  merge_kernel<<<2048, 64, 0, stream>>>(AOb, PO1, PM, PL);
  gemm_kernel<1><<<dim3(32, 8, 1), 256, 0, stream>>>(
      AOb, Wb, nullptr, nullptr, nullptr, out, nullptr);
}

// Round 9
// 114.081 us; speedup vs baseline: 1.9733x; 1.9733x over previous
//
#include <hip/hip_runtime.h>
#include <hip/hip_bf16.h>
#include <stdint.h>

typedef __attribute__((ext_vector_type(8))) short bf8;
typedef __attribute__((ext_vector_type(4))) float f4;

#define MFMA16(a, b, c) __builtin_amdgcn_mfma_f32_16x16x32_bf16((a), (b), (c), 0, 0, 0)

static __device__ __forceinline__ short f2b(float f) {
  uint32_t x = __float_as_uint(f);
  x += 0x7fffu + ((x >> 16) & 1u);
  return (short)(x >> 16);
}

// pack two nonnegative f32 into 2x bf16 (round-half-up, <0.5 ulp bias)
static __device__ __forceinline__ uint32_t pk2(float a, float b) {
  return ((__float_as_uint(a) + 0x8000u) >> 16) |
         ((__float_as_uint(b) + 0x8000u) & 0xffff0000u);
}

// async global->LDS, 16B per lane; LDS dest = wave-uniform base + lane*16
static __device__ __forceinline__ void gload16(const short* g, void* l) {
  __builtin_amdgcn_global_load_lds(
      (const __attribute__((address_space(1))) void*)g,
      (__attribute__((address_space(3))) void*)l, 16, 0, 0);
}

// fused: f32->bf16 convert (x -> xb, 4 weights -> Wb) + rope table build.
// blocks [0,4096): convert; blocks [4096,4352): tab[s*32+i] = (cos,sin)(s*invf_i)
__global__ void convert_kernel(const float* __restrict__ x,
                               const float* __restrict__ wq, const float* __restrict__ wk,
                               const float* __restrict__ wv, const float* __restrict__ wo,
                               short* __restrict__ xb, short* __restrict__ Wb,
                               float2* __restrict__ tab) {
  const int bid = blockIdx.x;
  if (bid >= 4096) {
    const int t = (bid - 4096) * 256 + threadIdx.x;
    const int s = t >> 5, i = t & 31;
    const float inv = powf(10000.0f, -(float)i * (1.0f / 32.0f));
    const float ang = (float)s * inv;
    float sv, cv;
    sincosf(ang, &sv, &cv);
    tab[t] = make_float2(cv, sv);
    return;
  }
  const size_t i = ((size_t)bid * 256 + threadIdx.x) * 8;
  const float* __restrict__ src;
  short* __restrict__ dst;
  if (i < 4194304u) {
    src = x + i;
    dst = xb + i;
  } else {
    const size_t j = i - 4194304u;
    const int z = (int)(j >> 20);
    const size_t o = j & 1048575u;
    src = (z == 0 ? wq : z == 1 ? wk : z == 2 ? wv : wo) + o;
    dst = Wb + j;
  }
  const float4 a = *(const float4*)src;
  const float4 b = *(const float4*)(src + 4);
  bf8 v;
  v[0] = f2b(a.x); v[1] = f2b(a.y); v[2] = f2b(a.z); v[3] = f2b(a.w);
  v[4] = f2b(b.x); v[5] = f2b(b.y); v[6] = f2b(b.z); v[7] = f2b(b.w);
  *(bf8*)dst = v;
}

// C = A @ W^T, pure-bf16. 128x128 tiles, BK=64, 4 waves each 64x64.
// Staging via global_load_lds (16B) with inverse-swizzled global source
// (rule-21: linear dest + inv-swz source + swz read).
// MODE 0: W = Wb[blockIdx.z], z<2 -> RoPE Q/K epilogue; z==2 -> V^T epilogue
// MODE 1: W = Wb[3] (Wo), f32 epilogue -> [m][n]
template <int MODE>
__launch_bounds__(256, 2)
__global__ void gemm_kernel(const short* __restrict__ Ab, const short* __restrict__ Wb,
                            short* __restrict__ Qo, short* __restrict__ Ko,
                            short* __restrict__ VTo, float* __restrict__ Fo,
                            const float2* __restrict__ rope) {
  constexpr int K = 1024;
  const int bm = blockIdx.x, bn = blockIdx.y;
  const int z = (MODE == 0) ? blockIdx.z : 3;
  const short* __restrict__ Bb = Wb + ((size_t)z << 20);

  __shared__ short As[128 * 64];
  __shared__ short Bs[128 * 64];

  const int tid = threadIdx.x;
  const int lane = tid & 63;
  const int wave = tid >> 6;
  const int wr = wave >> 1, wc = wave & 1;
  const int lg = lane >> 4, lr = lane & 15;

  f4 acc[4][4];
#pragma unroll
  for (int i = 0; i < 4; i++)
#pragma unroll
    for (int j = 0; j < 4; j++) {
      acc[i][j][0] = 0.f; acc[i][j][1] = 0.f;
      acc[i][j][2] = 0.f; acc[i][j][3] = 0.f;
    }

  const int kc = tid & 7;     // 16B k-chunk within 64-wide slice
  const int srow = tid >> 3;  // 0..31
  const int kcs = (kc ^ (srow & 7)) * 8;  // inverse-swizzled source chunk
  char* const Asw = (char*)As + wave * 1024;
  char* const Bsw = (char*)Bs + wave * 1024;

  for (int k0 = 0; k0 < K; k0 += 64) {
#pragma unroll
    for (int i = 0; i < 4; i++) {
      const int row = srow + i * 32;
      gload16(Ab + (size_t)(bm * 128 + row) * K + k0 + kcs, Asw + i * 4096);
      gload16(Bb + (size_t)(bn * 128 + row) * K + k0 + kcs, Bsw + i * 4096);
    }
    __syncthreads();
#pragma unroll
    for (int kk = 0; kk < 2; kk++) {
      bf8 af[4], bb[4];
#pragma unroll
      for (int mi = 0; mi < 4; mi++) {
        const int row = wr * 64 + mi * 16 + lr;
        const int lb = (row * 128 + kk * 64 + lg * 16) ^ ((row & 7) << 4);
        af[mi] = *(const bf8*)((const char*)As + lb);
      }
#pragma unroll
      for (int ni = 0; ni < 4; ni++) {
        const int row = wc * 64 + ni * 16 + lr;
        const int lb = (row * 128 + kk * 64 + lg * 16) ^ ((row & 7) << 4);
        bb[ni] = *(const bf8*)((const char*)Bs + lb);
      }
#pragma unroll
      for (int mi = 0; mi < 4; mi++)
#pragma unroll
        for (int ni = 0; ni < 4; ni++)
          acc[mi][ni] = MFMA16(af[mi], bb[ni], acc[mi][ni]);
    }
    __syncthreads();
  }

  if (MODE == 1) {
#pragma unroll
    for (int mi = 0; mi < 4; mi++) {
      const int m0 = bm * 128 + wr * 64 + mi * 16 + lg * 4;
#pragma unroll
      for (int ni = 0; ni < 4; ni++) {
        const int n = bn * 128 + wc * 64 + ni * 16 + lr;
#pragma unroll
        for (int r = 0; r < 4; r++)
          Fo[(size_t)(m0 + r) * 1024 + n] = acc[mi][ni][r];
      }
    }
    return;
  }

  if (z == 2) {  // V^T: [b][h][64][s]
#pragma unroll
    for (int mi = 0; mi < 4; mi++) {
      const int m0 = bm * 128 + wr * 64 + mi * 16 + lg * 4;
      const int b = m0 >> 11, s0 = m0 & 2047;
#pragma unroll
      for (int ni = 0; ni < 4; ni++) {
        const int n = bn * 128 + wc * 64 + ni * 16 + lr;
        ushort4 pk;
        pk.x = (unsigned short)f2b(acc[mi][ni][0]);
        pk.y = (unsigned short)f2b(acc[mi][ni][1]);
        pk.z = (unsigned short)f2b(acc[mi][ni][2]);
        pk.w = (unsigned short)f2b(acc[mi][ni][3]);
        *(ushort4*)(VTo + ((size_t)((b * 16 + (n >> 6)) * 64 + (n & 63))) * 2048 + s0) = pk;
      }
    }
  } else {  // Q or K with RoPE: [b][h][s][64]
    short* __restrict__ Out = (z == 0) ? Qo : Ko;
    // Q gets the attention scale folded with log2(e) so softmax can use exp2
    const float qscale = (z == 0) ? 0.18033688011112042f : 1.0f;  // 0.125*log2(e)
#pragma unroll
    for (int mi = 0; mi < 4; mi++) {
      const int m0 = bm * 128 + wr * 64 + mi * 16 + lg * 4;
      const int b = m0 >> 11, s0 = m0 & 2047;
#pragma unroll
      for (int ni = 0; ni < 4; ni++) {
        const int n = bn * 128 + wc * 64 + ni * 16 + lr;
        const int h = n >> 6, d = n & 63;
        const float sgn = (d & 1) ? 1.0f : -1.0f;
#pragma unroll
        for (int r = 0; r < 4; r++) {
          const float v = acc[mi][ni][r];
          const float p = __shfl_xor(v, 1);  // partner head-dim (d^1)
          const float2 cs = rope[((s0 + r) << 5) + (d >> 1)];
          const float res = (v * cs.x + sgn * p * cs.y) * qscale;
          Out[((size_t)(b * 16 + h) * 2048 + (s0 + r)) * 64 + d] = f2b(res);
        }
      }
    }
  }
}

// Flash attention, causal. 8-wave (512-thread) block owns 128 q-rows as 8
// consecutive 16-row wave-tiles. Per KV-block the block cooperatively stages
// K (8KB) + V^T (8KB) into double-buffered LDS via global_load_lds.
// 2-phase schedule: stage(next) || compute(cur); one __syncthreads per iter.
// Swapped QK^T + in-lane softmax + defer-max. qb assignment uses the
// complementary permutation T[u] = (u<8 ? 15-2u : 2u-16) so blocks id and
// id+256 (co-resident on a CU under round-robin dispatch) have qb pairs
// summing to 15 -> per-CU round-sum ~const (fixes R6's 24.7% occupancy tail).
__launch_bounds__(512, 4)
__global__ void attn_kernel(const short* __restrict__ Qg, const short* __restrict__ Kg,
                            const short* __restrict__ Vg, short* __restrict__ AO) {
  const int S = 2048;
  const int id = blockIdx.x;
  const int xcd = id & 7, slot = id >> 3;
  const int bh = xcd * 4 + (slot & 3);   // XCD-clustered head/batch
  const int u = id >> 5;                  // 0..15
  const int qb = (u < 8) ? (15 - 2 * u) : (2 * u - 16);  // complementary pairs
  const int tid = threadIdx.x;
  const int lane = tid & 63, wave = tid >> 6;
  const int lg = lane >> 4, lr = lane & 15;
  const short* __restrict__ Qp = Qg + (size_t)bh * S * 64;
  const short* __restrict__ Kp = Kg + (size_t)bh * S * 64;
  const short* __restrict__ Vp = Vg + (size_t)bh * 64 * S;

  __shared__ short KB[2][64 * 64];  // K tile, swizzled layout
  __shared__ short VB[2][64 * 64];  // V^T tile, swizzled layout
  __shared__ short PB[8][16 * 64];  // wave-private P tiles

  // staging indices: thread covers (row = tid>>3, chunk = tid&7) of each tile
  const int srow = tid >> 3;                 // 0..63
  const int kcs = ((tid & 7) ^ (srow & 7)) * 8;  // inverse-swizzled source chunk
  const size_t ksrc = (size_t)srow * 64 + kcs;   // + kvb*64
  const size_t vsrc = (size_t)srow * 2048 + kcs; // + kvb

  const int qbase = qb * 128 + wave * 16;
  const int my_nkv = (qbase + 79) >> 6;    // this wave's causal trip count
  const int blk_nkv = (qb * 128 + 191) >> 6;  // block max (wave 7)

  bf8 qf[2];
#pragma unroll
  for (int ks = 0; ks < 2; ks++)
    qf[ks] = *(const bf8*)(Qp + (size_t)(qbase + lr) * 64 + ks * 32 + lg * 8);

  f4 o[4];
#pragma unroll
  for (int dt = 0; dt < 4; dt++) {
    o[dt][0] = 0.f; o[dt][1] = 0.f; o[dt][2] = 0.f; o[dt][3] = 0.f;
  }
  float mrun = -1e30f, lsum = 0.f;

  char* const Pw = (char*)&PB[wave][0];
  const int rowoff = lr * 128;
  const int sw = (lr & 7) << 4;

  // prologue: stage tile 0 into buf 0
  gload16(Kp + ksrc, (char*)KB[0] + wave * 1024);
  gload16(Vp + vsrc, (char*)VB[0] + wave * 1024);
  __syncthreads();

  for (int kb = 0; kb < blk_nkv; kb++) {
    const int kvb = kb * 64;
    const int cur = kb & 1;

    // stage next tile into the other buffer (hidden under compute)
    if (kb + 1 < blk_nkv) {
      gload16(Kp + (size_t)(kvb + 64) * 64 + ksrc, (char*)KB[cur ^ 1] + wave * 1024);
      gload16(Vp + (size_t)(kvb + 64) + vsrc, (char*)VB[cur ^ 1] + wave * 1024);
    }

    if (kb < my_nkv) {
      const char* Kc = (const char*)KB[cur];
      const char* Vc = (const char*)VB[cur];

      // swapped QK^T: st[nt] = S^T[kv = kvb+nt*16+lg*4+r][q = qbase+lr]
      f4 st[4];
      __builtin_amdgcn_s_setprio(1);
#pragma unroll
      for (int nt = 0; nt < 4; nt++) {
        const int row = nt * 16 + lr;
        const int base = row * 128 + lg * 16;
        const int rsw = (row & 7) << 4;
        const bf8 k0 = *(const bf8*)(Kc + ((base) ^ rsw));
        const bf8 k1 = *(const bf8*)(Kc + ((base + 64) ^ rsw));
        f4 c;
        c[0] = 0.f; c[1] = 0.f; c[2] = 0.f; c[3] = 0.f;
        c = MFMA16(k0, qf[0], c);
        c = MFMA16(k1, qf[1], c);
        st[nt] = c;
      }
      __builtin_amdgcn_s_setprio(0);

      if ((kvb + 63) > qbase) {  // causal mask (last iter of this wave)
        const int q = qbase + lr;
#pragma unroll
        for (int nt = 0; nt < 4; nt++)
#pragma unroll
          for (int r = 0; r < 4; r++) {
            const int kv = kvb + nt * 16 + lg * 4 + r;
            if (kv > q) st[nt][r] = -1e9f;
          }
      }

      // per-q tile max: in-lane tree over 16 values + 2 cross-lg shfls
      float m0 = fmaxf(fmaxf(st[0][0], st[0][1]), fmaxf(st[0][2], st[0][3]));
#pragma unroll
      for (int nt = 1; nt < 4; nt++)
        m0 = fmaxf(m0, fmaxf(fmaxf(st[nt][0], st[nt][1]), fmaxf(st[nt][2], st[nt][3])));
      m0 = fmaxf(m0, __shfl_xor(m0, 16));
      m0 = fmaxf(m0, __shfl_xor(m0, 32));

      // defer-max: rescale only when tile max grew past threshold (exp2 domain)
      if (__any(m0 - mrun > 8.0f)) {
        const float mn = fmaxf(mrun, m0);
        const float corr = __builtin_amdgcn_exp2f(mrun - mn);
        mrun = mn;
        lsum *= corr;
#pragma unroll
        for (int r = 0; r < 4; r++) {
          const float co = __shfl(corr, (lg << 2) + r);  // o-layout q = lg*4+r
#pragma unroll
          for (int dt = 0; dt < 4; dt++) o[dt][r] *= co;
        }
      }

      // WAR guard: previous P reads drained (intra-wave)
      asm volatile("s_waitcnt lgkmcnt(0)" ::: "memory");

      // P = exp2(st - m); in-lane partial sums; pack 4 kv -> one b64 store
#pragma unroll
      for (int nt = 0; nt < 4; nt++) {
        const float p0 = __builtin_amdgcn_exp2f(st[nt][0] - mrun);
        const float p1 = __builtin_amdgcn_exp2f(st[nt][1] - mrun);
        const float p2 = __builtin_amdgcn_exp2f(st[nt][2] - mrun);
        const float p3 = __builtin_amdgcn_exp2f(st[nt][3] - mrun);
        lsum += (p0 + p1) + (p2 + p3);
        *(uint2*)(Pw + ((rowoff + nt * 32 + lg * 8) ^ sw)) = make_uint2(pk2(p0, p1), pk2(p2, p3));
      }

      // RAW guard: all lanes' P writes visible before fragment reads
      asm volatile("s_waitcnt lgkmcnt(0)" ::: "memory");

      bf8 pf[2];
#pragma unroll
      for (int ks = 0; ks < 2; ks++)
        pf[ks] = *(const bf8*)(Pw + ((rowoff + ks * 64 + lg * 16) ^ sw));

      __builtin_amdgcn_s_setprio(1);
#pragma unroll
      for (int dt = 0; dt < 4; dt++) {
        const int row = dt * 16 + lr;
        const int base = row * 128 + lg * 16;
        const int rsw = (row & 7) << 4;
        const bf8 v0 = *(const bf8*)(Vc + ((base) ^ rsw));
        const bf8 v1 = *(const bf8*)(Vc + ((base + 64) ^ rsw));
        o[dt] = MFMA16(pf[0], v0, o[dt]);
        o[dt] = MFMA16(pf[1], v1, o[dt]);
      }
      __builtin_amdgcn_s_setprio(0);
    }

    // __syncthreads drains vmcnt (stage complete) + lgkmcnt: next buffer ready
    __syncthreads();
  }

  // finalize: cross-lg sum reduce in swapped layout, redistribute 1/lsum
  float s = lsum;
  s += __shfl_xor(s, 16);
  s += __shfl_xor(s, 32);
  const float inv = 1.0f / s;
  float inv_o[4];
#pragma unroll
  for (int r = 0; r < 4; r++) inv_o[r] = __shfl(inv, (lg << 2) + r);

  const int b = bh >> 4, h = bh & 15;
#pragma unroll
  for (int r = 0; r < 4; r++) {
    const int q = qbase + lg * 4 + r;
#pragma unroll
    for (int dt = 0; dt < 4; dt++) {
      const int d = dt * 16 + lr;
      AO[((size_t)b * 2048 + q) * 1024 + h * 64 + d] = f2b(o[dt][r] * inv_o[r]);
    }
  }
}

extern "C" void kernel_launch(void* const* d_in, const int* in_sizes, int n_in,
                              void* d_out, int out_size, void* d_ws, size_t ws_size,
                              hipStream_t stream) {
  const float* x  = (const float*)d_in[0];
  const float* wq = (const float*)d_in[1];
  const float* wk = (const float*)d_in[2];
  const float* wv = (const float*)d_in[3];
  const float* wo = (const float*)d_in[4];
  float* out = (float*)d_out;

  char* ws = (char*)d_ws;
  short*  Qb  = (short*)(ws);                       // 8 MB  [b][h][s][64] bf16 (pre-scaled)
  short*  Kb  = (short*)(ws + (8ull  << 20));       // 8 MB
  short*  VTb = (short*)(ws + (16ull << 20));       // 8 MB  [b][h][64][s] bf16
  short*  AOb = (short*)(ws + (24ull << 20));       // 8 MB  [b][s][1024] bf16 (aliases xb)
  short*  xb  = AOb;                                // xb dead before attn writes AOb
  short*  Wb  = (short*)(ws + (32ull << 20));       // 8 MB  [4][1024][1024] bf16
  float2* tab = (float2*)(ws + (40ull << 20));      // 512 KB rope table

  convert_kernel<<<4352, 256, 0, stream>>>(x, wq, wk, wv, wo, xb, Wb, tab);
  gemm_kernel<0><<<dim3(32, 8, 3), 256, 0, stream>>>(
      xb, Wb, Qb, Kb, VTb, nullptr, tab);
  attn_kernel<<<512, 512, 0, stream>>>(Qb, Kb, VTb, AOb);
  gemm_kernel<1><<<dim3(32, 8, 1), 256, 0, stream>>>(
      AOb, Wb, nullptr, nullptr, nullptr, out, nullptr);
}